// Round 4
// baseline (3015.741 us; speedup 1.0000x reference)
//
#include <hip/hip_runtime.h>

#define NLVL 6
#define NN   32768
#define KFAN 8
#define FDIM 32
#define HDIM 256

typedef __attribute__((ext_vector_type(4))) float f32x4;
typedef __attribute__((ext_vector_type(8))) _Float16 f16x8;
typedef __attribute__((ext_vector_type(4))) unsigned short u16x4;

__device__ __forceinline__ float h2f(unsigned short u) {
    _Float16 h; __builtin_memcpy(&h, &u, 2); return (float)h;
}
__device__ __forceinline__ unsigned short f2h(float f) {
    _Float16 h = (_Float16)f;   // RNE
    unsigned short u; __builtin_memcpy(&u, &h, 2); return u;
}
__device__ __forceinline__ float tanh_fast(float x) {
    float e = __expf(2.0f * x);
    return 1.0f - 2.0f / (e + 1.0f);
}
__device__ __forceinline__ void gload16(const void* g, void* l) {
    __builtin_amdgcn_global_load_lds((const __attribute__((address_space(1))) void*)g,
                                     (__attribute__((address_space(3))) void*)l, 16, 0, 0);
}

// ---------------------------------------------------------------------------
// One GEMM layer: acc[MFR][4] += sA[rbase.., :KLEN] @ Wg[wcol.., :KLEN]^T
// A from LDS (XOR-swizzled rows of ROWB bytes), B streamed global->regs
// (weights L2-resident, compile-time row stride LDW for cheap addressing).
// Ping-pong prefetch, all buffer indices static after full unroll.
// ---------------------------------------------------------------------------
template<int KLEN, int ROWB, int MFR, int LDW>
__device__ __forceinline__ void layer_mm(const unsigned short* sA,
                                         const unsigned short* __restrict__ Wg,
                                         int rbase, int wcol, int lane,
                                         f32x4 (&acc)[MFR][4])
{
    const int fr = lane & 15, fq = lane >> 4;
    #pragma unroll
    for (int m = 0; m < MFR; ++m)
        #pragma unroll
        for (int n = 0; n < 4; ++n)
            acc[m][n] = (f32x4){0.f, 0.f, 0.f, 0.f};

    constexpr int NKS = KLEN / 32;
    f16x8 av[2][MFR], bv[2][4];
    const unsigned short* Wbase = Wg + (size_t)(wcol + fr) * LDW + fq * 8;

    auto ldB = [&](int ks, int buf) {
        #pragma unroll
        for (int n = 0; n < 4; ++n)
            bv[buf][n] = *(const f16x8*)(Wbase + n * 16 * LDW + ks * 32);
    };
    auto ldA = [&](int ks, int buf) {
        #pragma unroll
        for (int m = 0; m < MFR; ++m) {
            const int rr = rbase + m * 16 + fr;
            const int byt = rr * ROWB + ((ks * 64 + fq * 16) ^ ((rr & 7) << 4));
            av[buf][m] = *(const f16x8*)((const char*)sA + byt);
        }
    };

    ldA(0, 0); ldB(0, 0);
    #pragma unroll
    for (int s = 0; s < NKS; ++s) {
        if (s + 1 < NKS) { ldA(s + 1, (s + 1) & 1); ldB(s + 1, (s + 1) & 1); }
        #pragma unroll
        for (int m = 0; m < MFR; ++m)
            #pragma unroll
            for (int n = 0; n < 4; ++n)
                acc[m][n] = __builtin_amdgcn_mfma_f32_16x16x32_f16(av[s & 1][m], bv[s & 1][n], acc[m][n], 0, 0, 0);
    }
}

// ---------------------------------------------------------------------------
// Fused 3-layer resnet: out = tanh(W3 @ (tanh(W2@tanh(W1@x+b1)+b2) + x) + b3)
// BM rows/block, 8 waves, LDS <= 64KB -> 2 blocks/CU (4 waves/SIMD).
// x staged to sX (or gather-summed if GATHER); h1/h2 live in sH.
// Layer-1 K-extent = K1 (comb-big: x = [e,0] -> K1=256).
// ---------------------------------------------------------------------------
template<int BM, int KD, int K1, bool GATHER, bool F32OUT>
__global__ __launch_bounds__(512, 4)
void resnet_fused(const unsigned short* __restrict__ X, int ldx,
                  const int* __restrict__ gidx,
                  const unsigned short* __restrict__ gsrc,
                  const unsigned short* __restrict__ W1, const float* __restrict__ b1,
                  const unsigned short* __restrict__ W2, const float* __restrict__ b2,
                  const unsigned short* __restrict__ W3, const float* __restrict__ b3,
                  unsigned short* __restrict__ outB, int ldo,
                  float* __restrict__ outF)
{
    __shared__ __align__(16) unsigned short sX[BM * K1];
    __shared__ __align__(16) unsigned short sH[BM * KD];
    constexpr int ROWBX = K1 * 2, ROWBH = KD * 2;

    const int tid = threadIdx.x, lane = tid & 63, wid = tid >> 6;
    const int brow = blockIdx.x * BM;
    const int fr = lane & 15, fq = lane >> 4;

    // ---- stage x -> sX (swizzled) ----
    if (GATHER) {
        constexpr int CB = K1 / 8;
        #pragma unroll
        for (int r = 0; r < BM * CB / 512; ++r) {
            const int i = r * 512 + tid;
            const int row = i / CB, cb = i % CB;
            const int* ip = gidx + (size_t)(brow + row) * KFAN;
            float s[8] = {0.f, 0.f, 0.f, 0.f, 0.f, 0.f, 0.f, 0.f};
            #pragma unroll
            for (int k = 0; k < KFAN; ++k) {
                f16x8 v = *(const f16x8*)(gsrc + (size_t)ip[k] * HDIM + cb * 8);
                #pragma unroll
                for (int j = 0; j < 8; ++j) s[j] += (float)v[j];
            }
            f16x8 o;
            #pragma unroll
            for (int j = 0; j < 8; ++j) o[j] = (_Float16)s[j];
            *(f16x8*)((char*)sX + row * ROWBX + ((cb * 16) ^ ((row & 7) << 4))) = o;
        }
    } else {
        constexpr int ROUNDS = BM * K1 * 2 / (512 * 16);
        #pragma unroll
        for (int r = 0; r < ROUNDS; ++r) {
            const int lin = (r * 512 + tid) * 16;        // this lane's dest byte
            const int row = lin / ROWBX;
            const int cb  = (lin % ROWBX) >> 4;
            const int scb = cb ^ (row & 7);              // pre-swizzled source block
            gload16(X + (size_t)(brow + row) * ldx + scb * 8,
                    (char*)sX + (lin - lane * 16));      // wave-uniform LDS base
        }
    }
    __syncthreads();

    // ---- wave -> tile mapping ----
    constexpr int NWC12 = KD / 64;            // 4 (small) or 8 (big)
    constexpr int NWR12 = 8 / NWC12;          // 2 or 1
    constexpr int RPG12 = BM / NWR12;         // 32 rows per group (both)
    constexpr int MFR12 = RPG12 / 16;         // 2
    const int wc12 = (wid % NWC12) * 64;
    const int rb12 = (wid / NWC12) * RPG12;

    // ---- layer 1: h1 = tanh(x @ W1^T + b1) -> sH ----
    {
        f32x4 a1[MFR12][4];
        layer_mm<K1, ROWBX, MFR12, KD>(sX, W1, rb12, wc12, lane, a1);
        #pragma unroll
        for (int m = 0; m < MFR12; ++m)
            #pragma unroll
            for (int n = 0; n < 4; ++n) {
                const int col = wc12 + n * 16 + fr;
                const float bb = b1[col];
                #pragma unroll
                for (int j = 0; j < 4; ++j) {
                    const int row = rb12 + m * 16 + fq * 4 + j;
                    const float v = tanh_fast(a1[m][n][j] + bb);
                    *(unsigned short*)((char*)sH + row * ROWBH + ((col * 2) ^ ((row & 7) << 4))) = f2h(v);
                }
            }
    }
    __syncthreads();

    // ---- layer 2: h2 = tanh(h1 @ W2^T + b2) + x -> sH ----
    {
        f32x4 a2[MFR12][4];
        layer_mm<KD, ROWBH, MFR12, KD>(sH, W2, rb12, wc12, lane, a2);
        #pragma unroll
        for (int m = 0; m < MFR12; ++m)
            #pragma unroll
            for (int n = 0; n < 4; ++n) {
                const int col = wc12 + n * 16 + fr;
                const float bb = b2[col];
                #pragma unroll
                for (int j = 0; j < 4; ++j) {
                    const int row = rb12 + m * 16 + fq * 4 + j;
                    float v = tanh_fast(a2[m][n][j] + bb);
                    if (col < K1)
                        v += h2f(*(const unsigned short*)((const char*)sX + row * ROWBX + ((col * 2) ^ ((row & 7) << 4))));
                    a2[m][n][j] = v;
                }
            }
        __syncthreads();   // all waves done READING sH before overwrite
        #pragma unroll
        for (int m = 0; m < MFR12; ++m)
            #pragma unroll
            for (int n = 0; n < 4; ++n) {
                const int col = wc12 + n * 16 + fr;
                #pragma unroll
                for (int j = 0; j < 4; ++j) {
                    const int row = rb12 + m * 16 + fq * 4 + j;
                    *(unsigned short*)((char*)sH + row * ROWBH + ((col * 2) ^ ((row & 7) << 4))) = f2h(a2[m][n][j]);
                }
            }
    }
    __syncthreads();

    // ---- layer 3: out = tanh((h2+x) @ W3^T + b3), N=256 ----
    {
        constexpr int RPG3 = BM / 2;          // 32 (small) or 16 (big)
        constexpr int MFR3 = RPG3 / 16;       // 2 or 1
        const int wc3 = (wid & 3) * 64;
        const int rb3 = (wid >> 2) * RPG3;
        f32x4 a3[MFR3][4];
        layer_mm<KD, ROWBH, MFR3, KD>(sH, W3, rb3, wc3, lane, a3);
        #pragma unroll
        for (int m = 0; m < MFR3; ++m)
            #pragma unroll
            for (int n = 0; n < 4; ++n) {
                const int col = wc3 + n * 16 + fr;
                const float bb = b3[col];
                #pragma unroll
                for (int j = 0; j < 4; ++j) {
                    const int row = rb3 + m * 16 + fq * 4 + j;
                    const float v = tanh_fast(a3[m][n][j] + bb);
                    const size_t gr = (size_t)(brow + row);
                    outB[gr * ldo + col] = f2h(v);
                    if (F32OUT) outF[gr * HDIM + col] = v;
                }
            }
    }
}

// ---------------------------------------------------------------------------
// Embed: e = tanh(feats[N,32] @ We[256,32]^T + be) -> fp16 (+ optional f32)
// ---------------------------------------------------------------------------
template<bool F32OUT>
__global__ __launch_bounds__(256)
void embed_kernel(const float* __restrict__ feats,
                  const float* __restrict__ We,
                  const float* __restrict__ be,
                  unsigned short* __restrict__ outB, int ldo,
                  float* __restrict__ outF)
{
    __shared__ float sW[256 * 33];   // +1 pad: kills bank conflicts on t*33+k
    __shared__ float sF[16 * 32];
    const int t = threadIdx.x;
    #pragma unroll
    for (int i = 0; i < 32; ++i) {
        int idx = t + 256 * i;
        sW[(idx >> 5) * 33 + (idx & 31)] = We[idx];
    }
    const size_t base = (size_t)blockIdx.x * 16;
    for (int i = t; i < 16 * 32; i += 256) sF[i] = feats[base * 32 + i];
    __syncthreads();

    const float bb = be[t];
    for (int r = 0; r < 16; ++r) {
        float a = bb;
        #pragma unroll
        for (int k = 0; k < 32; ++k) a += sF[r * 32 + k] * sW[t * 33 + k];
        const float v = tanh_fast(a);
        const size_t row = base + r;
        outB[row * ldo + t] = f2h(v);
        if (F32OUT) outF[row * HDIM + t] = v;
    }
}

// ---------------------------------------------------------------------------
// fp32 -> fp16 weight conversion
// ---------------------------------------------------------------------------
__global__ __launch_bounds__(256)
void cvt_kernel(const float* __restrict__ in, unsigned short* __restrict__ out, int n4)
{
    const int i = blockIdx.x * 256 + threadIdx.x;
    if (i >= n4) return;
    const float4 v = ((const float4*)in)[i];
    u16x4 o;
    o[0] = f2h(v.x); o[1] = f2h(v.y); o[2] = f2h(v.z); o[3] = f2h(v.w);
    ((u16x4*)out)[i] = o;
}

// ---------------------------------------------------------------------------
extern "C" void kernel_launch(void* const* d_in, const int* in_sizes, int n_in,
                              void* d_out, int out_size, void* d_ws, size_t ws_size,
                              hipStream_t stream)
{
    const float* feats    = (const float*)d_in[0];
    const int*   pred_idx = (const int*)d_in[1];
    const float* We       = (const float*)d_in[2];
    const float* be       = (const float*)d_in[3];
    const float* rs_W1    = (const float*)d_in[4];
    const float* rs_b1    = (const float*)d_in[5];
    const float* rs_W2    = (const float*)d_in[6];
    const float* rs_b2    = (const float*)d_in[7];
    const float* rs_W3    = (const float*)d_in[8];
    const float* rs_b3    = (const float*)d_in[9];
    const float* rc_W1    = (const float*)d_in[10];
    const float* rc_b1    = (const float*)d_in[11];
    const float* rc_W2    = (const float*)d_in[12];
    const float* rc_b2    = (const float*)d_in[13];
    const float* rc_W3    = (const float*)d_in[14];
    const float* rc_b3    = (const float*)d_in[15];
    float* out = (float*)d_out;

    // ---- workspace layout (fp16 everywhere) ----
    char* ws = (char*)d_ws;
    size_t off = 0;
    auto alloc = [&](size_t bytes) -> unsigned short* {
        unsigned short* p = (unsigned short*)(ws + off);
        off += (bytes + 255) & ~(size_t)255;
        return p;
    };
    unsigned short* rcW1b = alloc((size_t)6 * 512 * 512 * 2);
    unsigned short* rcW2b = alloc((size_t)6 * 512 * 512 * 2);
    unsigned short* rcW3b = alloc((size_t)6 * 256 * 512 * 2);
    unsigned short* rsW1b = alloc((size_t)12 * 256 * 256 * 2);
    unsigned short* rsW2b = alloc((size_t)12 * 256 * 256 * 2);
    unsigned short* rsW3b = alloc((size_t)12 * 256 * 256 * 2);
    unsigned short* xcat  = alloc((size_t)NN * 256 * 2);   // e (embed out)
    unsigned short* p0    = alloc((size_t)NN * 512 * 2);   // x2cat = [e', r]
    unsigned short* Tb    = alloc((size_t)NN * 256 * 2);   // big-resnet outputs
    unsigned short* q0    = alloc((size_t)NN * 256 * 2);   // msg chain temp
    unsigned short* ebfA  = alloc((size_t)NN * 256 * 2);
    unsigned short* ebfB  = alloc((size_t)NN * 256 * 2);
    (void)ws_size; (void)in_sizes; (void)n_in; (void)out_size;

    // ---- convert weights fp32 -> fp16 ----
    auto cvt = [&](const float* src, unsigned short* dst, int n) {
        int n4 = n / 4;
        cvt_kernel<<<dim3((n4 + 255) / 256), dim3(256), 0, stream>>>(src, dst, n4);
    };
    cvt(rc_W1, rcW1b, 6 * 512 * 512);
    cvt(rc_W2, rcW2b, 6 * 512 * 512);
    cvt(rc_W3, rcW3b, 6 * 256 * 512);
    cvt(rs_W1, rsW1b, 12 * 256 * 256);
    cvt(rs_W2, rsW2b, 12 * 256 * 256);
    cvt(rs_W3, rsW3b, 12 * 256 * 256);

    // ---- fused resnet launchers ----
    auto smallRN = [&](int i, const unsigned short* x, int ldx,
                       unsigned short* ob, int ldo, float* of,
                       const int* gidx, const unsigned short* gsrc) {
        const unsigned short* w1 = rsW1b + (size_t)i * 256 * 256;
        const unsigned short* w2 = rsW2b + (size_t)i * 256 * 256;
        const unsigned short* w3 = rsW3b + (size_t)i * 256 * 256;
        const float* B1 = rs_b1 + i * 256;
        const float* B2 = rs_b2 + i * 256;
        const float* B3 = rs_b3 + i * 256;
        if (gidx)
            resnet_fused<64, 256, 256, true, false><<<dim3(NN / 64), dim3(512), 0, stream>>>(
                nullptr, 0, gidx, gsrc, w1, B1, w2, B2, w3, B3, ob, ldo, nullptr);
        else if (of)
            resnet_fused<64, 256, 256, false, true><<<dim3(NN / 64), dim3(512), 0, stream>>>(
                x, ldx, nullptr, nullptr, w1, B1, w2, B2, w3, B3, ob, ldo, of);
        else
            resnet_fused<64, 256, 256, false, false><<<dim3(NN / 64), dim3(512), 0, stream>>>(
                x, ldx, nullptr, nullptr, w1, B1, w2, B2, w3, B3, ob, ldo, nullptr);
    };
    auto bigRN = [&](int i, bool halfK, const unsigned short* x, int ldx, unsigned short* ob) {
        const unsigned short* w1 = rcW1b + (size_t)i * 512 * 512;
        const unsigned short* w2 = rcW2b + (size_t)i * 512 * 512;
        const unsigned short* w3 = rcW3b + (size_t)i * 256 * 512;
        const float* B1 = rc_b1 + i * 512;
        const float* B2 = rc_b2 + i * 512;
        const float* B3 = rc_b3 + i * 256;
        if (halfK)
            resnet_fused<32, 512, 256, false, false><<<dim3(NN / 32), dim3(512), 0, stream>>>(
                x, ldx, nullptr, nullptr, w1, B1, w2, B2, w3, B3, ob, 256, nullptr);
        else
            resnet_fused<32, 512, 512, false, false><<<dim3(NN / 32), dim3(512), 0, stream>>>(
                x, ldx, nullptr, nullptr, w1, B1, w2, B2, w3, B3, ob, 256, nullptr);
    };

    unsigned short* ebp = ebfA;   // embeds[l-1] (fp16)
    unsigned short* ebc = ebfB;   // embeds[l]

    // level 0
    embed_kernel<true><<<dim3(NN / 16), dim3(256), 0, stream>>>(
        feats, We, be, ebp, 256, out);

    for (int l = 1; l < NLVL; ++l) {
        const int d = (l - 1 < 2) ? (l - 1) : 2;
        const float* fl = feats + (size_t)l * NN * FDIM;
        const int* idx_l = pred_idx + (size_t)(l - 1) * NN * KFAN;

        // e = tanh(feats @ We^T + be)
        embed_kernel<false><<<dim3(NN / 16), dim3(256), 0, stream>>>(
            fl, We, be, xcat, 256, nullptr);

        // comb: T = tanh(big(3+d, [e,0])) [K1=256]; e' = tanh(small(9+d, T))
        bigRN(3 + d, true, xcat, 256, Tb);
        smallRN(9 + d, Tb, 256, p0, 512, nullptr, nullptr, nullptr);        // e' -> x2[:, :256]

        // msg: r = tanh(small(2d+1, tanh(small(2d, gathersum(ebp)))))
        smallRN(2 * d,     nullptr, 0, q0, 256, nullptr, idx_l, ebp);        // gather fused
        smallRN(2 * d + 1, q0, 256, p0 + 256, 512, nullptr, nullptr, nullptr); // r -> x2[:, 256:]

        // node: T = tanh(big(d, [e', r])); e = tanh(small(6+d, T))
        bigRN(d, false, p0, 512, Tb);
        smallRN(6 + d, Tb, 256, ebc, 256, out + (size_t)l * NN * HDIM, nullptr, nullptr);

        unsigned short* tmp = ebp; ebp = ebc; ebc = tmp;
    }
}

// Round 5
// 2608.164 us; speedup vs baseline: 1.1563x; 1.1563x over previous
//
#include <hip/hip_runtime.h>

#define NLVL 6
#define NN   32768
#define KFAN 8
#define FDIM 32
#define HDIM 256

typedef __attribute__((ext_vector_type(4))) float f32x4;
typedef __attribute__((ext_vector_type(8))) _Float16 f16x8;
typedef __attribute__((ext_vector_type(4))) unsigned short u16x4;

__device__ __forceinline__ float h2f(unsigned short u) {
    _Float16 h; __builtin_memcpy(&h, &u, 2); return (float)h;
}
__device__ __forceinline__ unsigned short f2h(float f) {
    _Float16 h = (_Float16)f;   // RNE
    unsigned short u; __builtin_memcpy(&u, &h, 2); return u;
}
__device__ __forceinline__ float tanh_fast(float x) {
    float e = __expf(2.0f * x);
    return 1.0f - 2.0f / (e + 1.0f);
}
__device__ __forceinline__ void gload16(const void* g, void* l) {
    __builtin_amdgcn_global_load_lds((const __attribute__((address_space(1))) void*)g,
                                     (__attribute__((address_space(3))) void*)l, 16, 0, 0);
}

// ---------------------------------------------------------------------------
// GEMM descriptor: out = tanh(A[M,K] @ B[N,K]^T + bias) [+ res if col<resW]
// M = 32768 fixed (nbx = 256 blocks); nblk = 256 * (N/128).
// ---------------------------------------------------------------------------
struct GDesc {
    const unsigned short* A;
    const unsigned short* B;
    const float* bias;
    const unsigned short* res;   // nullable
    unsigned short* outB;
    float* outF;                 // nullable (f32 mirror, ld = HDIM)
    int lda, ldb, ldr, ldo, resW, K, nblk;
};

// ---------------------------------------------------------------------------
// Batched fp16 B^T GEMM (r2-proven core): 128x128 tile, BK=64, 4 waves 2x2.
// Two descriptors per launch; block picks by range (wave-uniform).
// LDS XOR-swizzled both-sides (pre-swizzled global src + swizzled ds_read).
// ---------------------------------------------------------------------------
__global__ __launch_bounds__(256)
void gemm_batch(GDesc d0, GDesc d1, int nblk0)
{
    const bool sec = (int)blockIdx.x >= nblk0;
    const GDesc& d = sec ? d1 : d0;
    const int bx = sec ? ((int)blockIdx.x - nblk0) : (int)blockIdx.x;
    const int brow = (bx & 255) * 128;
    const int bcol = (bx >> 8) * 128;

    __shared__ __align__(16) unsigned short sA[128 * 64];
    __shared__ __align__(16) unsigned short sB[128 * 64];

    const int tid  = threadIdx.x;
    const int wid  = tid >> 6;
    const int lane = tid & 63;
    const int wr   = wid >> 1, wc = wid & 1;        // wave quadrant (2x2)
    const int fr   = lane & 15, fq = lane >> 4;     // fragment row / k-group
    const int srow = lane >> 3;                     // staging row within chunk
    const int scol = ((lane & 7) ^ srow) * 8;       // pre-swizzled 16B col-block

    const int lda = d.lda, ldb = d.ldb, K = d.K;
    f32x4 acc[4][4] = {};

    for (int k0 = 0; k0 < K; k0 += 64) {
        #pragma unroll
        for (int it = 0; it < 4; ++it) {
            const int c = wid * 4 + it;             // chunk 0..15 (wave-uniform)
            const int r = c * 8 + srow;             // tile row 0..127
            gload16(d.A + (size_t)(brow + r) * lda + k0 + scol, sA + c * 512);
            gload16(d.B + (size_t)(bcol + r) * ldb + k0 + scol, sB + c * 512);
        }
        __syncthreads();
        #pragma unroll
        for (int ks = 0; ks < 2; ++ks) {            // two K=32 sub-steps
            f16x8 av[4], bv[4];
            #pragma unroll
            for (int m = 0; m < 4; ++m) {
                const int r = wr * 64 + m * 16 + fr;
                const int b = r * 128 + ((ks * 64 + fq * 16) ^ ((r & 7) << 4));
                av[m] = *(const f16x8*)((const char*)sA + b);
            }
            #pragma unroll
            for (int n = 0; n < 4; ++n) {
                const int r = wc * 64 + n * 16 + fr;
                const int b = r * 128 + ((ks * 64 + fq * 16) ^ ((r & 7) << 4));
                bv[n] = *(const f16x8*)((const char*)sB + b);
            }
            #pragma unroll
            for (int m = 0; m < 4; ++m)
                #pragma unroll
                for (int n = 0; n < 4; ++n)
                    acc[m][n] = __builtin_amdgcn_mfma_f32_16x16x32_f16(av[m], bv[n], acc[m][n], 0, 0, 0);
        }
        __syncthreads();
    }

    // epilogue: C/D layout col = lane&15, row = (lane>>4)*4 + j  [m89-verified]
    const unsigned short* res = d.res;
    #pragma unroll
    for (int m = 0; m < 4; ++m) {
        #pragma unroll
        for (int n = 0; n < 4; ++n) {
            const int col = bcol + wc * 64 + n * 16 + fr;
            const float bb = d.bias[col];
            #pragma unroll
            for (int j = 0; j < 4; ++j) {
                const int row = brow + wr * 64 + m * 16 + fq * 4 + j;
                float v = acc[m][n][j] + bb;
                v = tanh_fast(v);
                if (res && col < d.resW) v += h2f(res[(size_t)row * d.ldr + col]);
                d.outB[(size_t)row * d.ldo + col] = f2h(v);
                if (d.outF) d.outF[(size_t)row * HDIM + col] = v;
            }
        }
    }
}

// ---------------------------------------------------------------------------
// Embed ALL levels: e_l = tanh(feats[l] @ We^T + be) -> ebuf[l] (fp16);
// level 0 also mirrored to out[0] (f32) since embeds[0] = embed_op(feats[0]).
// ---------------------------------------------------------------------------
__global__ __launch_bounds__(256)
void embed_all(const float* __restrict__ feats,
               const float* __restrict__ We,
               const float* __restrict__ be,
               unsigned short* __restrict__ ebuf,
               float* __restrict__ out0)
{
    __shared__ float sW[256 * 33];   // +1 pad: kills bank conflicts on t*33+k
    __shared__ float sF[16 * 32];
    const int l   = blockIdx.x >> 11;       // / 2048
    const int blk = blockIdx.x & 2047;
    const int t = threadIdx.x;
    #pragma unroll
    for (int i = 0; i < 32; ++i) {
        int idx = t + 256 * i;
        sW[(idx >> 5) * 33 + (idx & 31)] = We[idx];
    }
    const size_t base = (size_t)blk * 16;
    const float* fl = feats + (size_t)l * NN * FDIM;
    for (int i = t; i < 16 * 32; i += 256) sF[i] = fl[base * 32 + i];
    __syncthreads();

    unsigned short* ob = ebuf + (size_t)l * NN * HDIM;
    const float bb = be[t];
    for (int r = 0; r < 16; ++r) {
        float a = bb;
        #pragma unroll
        for (int k = 0; k < 32; ++k) a += sF[r * 32 + k] * sW[t * 33 + k];
        const float v = tanh_fast(a);
        const size_t row = base + r;
        ob[row * HDIM + t] = f2h(v);
        if (l == 0) out0[row * HDIM + t] = v;
    }
}

// ---------------------------------------------------------------------------
// Gather-sum: msg[n,:] = sum_{k<8} e[idx[n,k],:]  (fp16 in, fp32 acc, fp16 out)
// ---------------------------------------------------------------------------
__global__ __launch_bounds__(256)
void gather_kernel(const unsigned short* __restrict__ ehalf,
                   const int* __restrict__ idx,
                   unsigned short* __restrict__ msg)
{
    const int n = blockIdx.x;
    const int t = threadIdx.x;
    const int* row = idx + (size_t)n * KFAN;
    float s = 0.f;
    #pragma unroll
    for (int k = 0; k < KFAN; ++k)
        s += h2f(ehalf[(size_t)row[k] * HDIM + t]);
    msg[(size_t)n * HDIM + t] = f2h(s);
}

// ---------------------------------------------------------------------------
// fp32 -> fp16 weight conversion
// ---------------------------------------------------------------------------
__global__ __launch_bounds__(256)
void cvt_kernel(const float* __restrict__ in, unsigned short* __restrict__ out, int n4)
{
    const int i = blockIdx.x * 256 + threadIdx.x;
    if (i >= n4) return;
    const float4 v = ((const float4*)in)[i];
    u16x4 o;
    o[0] = f2h(v.x); o[1] = f2h(v.y); o[2] = f2h(v.z); o[3] = f2h(v.w);
    ((u16x4*)out)[i] = o;
}

// ---------------------------------------------------------------------------
extern "C" void kernel_launch(void* const* d_in, const int* in_sizes, int n_in,
                              void* d_out, int out_size, void* d_ws, size_t ws_size,
                              hipStream_t stream)
{
    const float* feats    = (const float*)d_in[0];
    const int*   pred_idx = (const int*)d_in[1];
    const float* We       = (const float*)d_in[2];
    const float* be       = (const float*)d_in[3];
    const float* rs_b1    = (const float*)d_in[5];
    const float* rs_b2    = (const float*)d_in[7];
    const float* rs_b3    = (const float*)d_in[9];
    const float* rc_b1    = (const float*)d_in[11];
    const float* rc_b2    = (const float*)d_in[13];
    const float* rc_b3    = (const float*)d_in[15];
    float* out = (float*)d_out;

    // ---- workspace layout (fp16 everywhere) ----
    char* ws = (char*)d_ws;
    size_t off = 0;
    auto alloc = [&](size_t bytes) -> unsigned short* {
        unsigned short* p = (unsigned short*)(ws + off);
        off += (bytes + 255) & ~(size_t)255;
        return p;
    };
    unsigned short* rcW1b = alloc((size_t)6 * 512 * 512 * 2);
    unsigned short* rcW2b = alloc((size_t)6 * 512 * 512 * 2);
    unsigned short* rcW3b = alloc((size_t)6 * 256 * 512 * 2);
    unsigned short* rsW1b = alloc((size_t)12 * 256 * 256 * 2);
    unsigned short* rsW2b = alloc((size_t)12 * 256 * 256 * 2);
    unsigned short* rsW3b = alloc((size_t)12 * 256 * 256 * 2);
    unsigned short* ebuf  = alloc((size_t)NLVL * NN * 256 * 2);  // embed_op all levels
    unsigned short* p0    = alloc((size_t)NN * 512 * 2);   // x2cat = [e', r]
    unsigned short* p1    = alloc((size_t)NN * 512 * 2);   // big h1
    unsigned short* p2    = alloc((size_t)NN * 512 * 2);   // big h2
    unsigned short* Tb    = alloc((size_t)NN * 256 * 2);   // big-resnet outputs
    unsigned short* q0    = alloc((size_t)NN * 256 * 2);
    unsigned short* q1    = alloc((size_t)NN * 256 * 2);
    unsigned short* q2    = alloc((size_t)NN * 256 * 2);
    unsigned short* q3    = alloc((size_t)NN * 256 * 2);
    unsigned short* msgb  = alloc((size_t)NN * 256 * 2);
    unsigned short* ebfA  = alloc((size_t)NN * 256 * 2);
    unsigned short* ebfB  = alloc((size_t)NN * 256 * 2);
    (void)ws_size; (void)in_sizes; (void)n_in; (void)out_size;

    // ---- convert weights fp32 -> fp16 ----
    auto cvt = [&](const float* src, unsigned short* dst, int n) {
        int n4 = n / 4;
        cvt_kernel<<<dim3((n4 + 255) / 256), dim3(256), 0, stream>>>(src, dst, n4);
    };
    cvt((const float*)d_in[10], rcW1b, 6 * 512 * 512);
    cvt((const float*)d_in[12], rcW2b, 6 * 512 * 512);
    cvt((const float*)d_in[14], rcW3b, 6 * 256 * 512);
    cvt((const float*)d_in[4],  rsW1b, 12 * 256 * 256);
    cvt((const float*)d_in[6],  rsW2b, 12 * 256 * 256);
    cvt((const float*)d_in[8],  rsW3b, 12 * 256 * 256);

    // ---- all embed_ops upfront (depend only on feats) ----
    embed_all<<<dim3(NLVL * (NN / 16)), dim3(256), 0, stream>>>(feats, We, be, ebuf, out);

    // ---- descriptor helpers ----
    auto D = [&](const unsigned short* A, int lda, const unsigned short* B, int ldb,
                 int N, int K, const float* bias,
                 const unsigned short* res, int ldr, int resW,
                 unsigned short* ob, int ldo, float* of) -> GDesc {
        GDesc g;
        g.A = A; g.B = B; g.bias = bias; g.res = res; g.outB = ob; g.outF = of;
        g.lda = lda; g.ldb = ldb; g.ldr = ldr; g.ldo = ldo; g.resW = resW;
        g.K = K; g.nblk = 256 * (N / 128);
        return g;
    };
    GDesc Z; Z.nblk = 0;
    auto GB = [&](const GDesc& a, const GDesc& b) {
        gemm_batch<<<dim3(a.nblk + b.nblk), dim3(256), 0, stream>>>(a, b, a.nblk);
    };

    const unsigned short* ep = ebuf;   // embeds[l-1]: level 0 final = embed_op(0)
    unsigned short* ebc = ebfA;
    unsigned short* ebn = ebfB;

    for (int l = 1; l < NLVL; ++l) {
        const int d = (l - 1 < 2) ? (l - 1) : 2;
        const unsigned short* el = ebuf + (size_t)l * NN * 256;  // embed_op(l)
        const int* idx_l = pred_idx + (size_t)(l - 1) * NN * KFAN;

        const unsigned short* cw1 = rcW1b + (size_t)(3 + d) * 512 * 512;
        const unsigned short* cw2 = rcW2b + (size_t)(3 + d) * 512 * 512;
        const unsigned short* cw3 = rcW3b + (size_t)(3 + d) * 256 * 512;
        const unsigned short* nw1 = rcW1b + (size_t)d * 512 * 512;
        const unsigned short* nw2 = rcW2b + (size_t)d * 512 * 512;
        const unsigned short* nw3 = rcW3b + (size_t)d * 256 * 512;
        auto sw = [&](const unsigned short* base, int i) { return base + (size_t)i * 256 * 256; };

        // msg gather (msgb <- sum of predecessor embeds from prev level)
        gather_kernel<<<dim3(NN), dim3(256), 0, stream>>>(ep, idx_l, msgb);

        // C1 || M1    (comb big layer1: x=[e,0] -> K=256 on first 256 W-cols)
        GB(D(el, 256, cw1, 512, 512, 256, rc_b1 + (3 + d) * 512, nullptr, 0, 0, p1, 512, nullptr),
           D(msgb, 256, sw(rsW1b, 2 * d), 256, 256, 256, rs_b1 + (2 * d) * 256, nullptr, 0, 0, q0, 256, nullptr));
        // C2 || M2
        GB(D(p1, 512, cw2, 512, 512, 512, rc_b2 + (3 + d) * 512, el, 256, 256, p2, 512, nullptr),
           D(q0, 256, sw(rsW2b, 2 * d), 256, 256, 256, rs_b2 + (2 * d) * 256, msgb, 256, 256, q1, 256, nullptr));
        // C3 || M3
        GB(D(p2, 512, cw3, 512, 256, 512, rc_b3 + (3 + d) * 256, nullptr, 0, 0, Tb, 256, nullptr),
           D(q1, 256, sw(rsW3b, 2 * d), 256, 256, 256, rs_b3 + (2 * d) * 256, nullptr, 0, 0, q2, 256, nullptr));
        // S1 || M4
        GB(D(Tb, 256, sw(rsW1b, 9 + d), 256, 256, 256, rs_b1 + (9 + d) * 256, nullptr, 0, 0, q0, 256, nullptr),
           D(q2, 256, sw(rsW1b, 2 * d + 1), 256, 256, 256, rs_b1 + (2 * d + 1) * 256, nullptr, 0, 0, q3, 256, nullptr));
        // S2 || M5
        GB(D(q0, 256, sw(rsW2b, 9 + d), 256, 256, 256, rs_b2 + (9 + d) * 256, Tb, 256, 256, q1, 256, nullptr),
           D(q3, 256, sw(rsW2b, 2 * d + 1), 256, 256, 256, rs_b2 + (2 * d + 1) * 256, q2, 256, 256, msgb, 256, nullptr));
        // S3 || M6   -> p0 = [e', r]
        GB(D(q1, 256, sw(rsW3b, 9 + d), 256, 256, 256, rs_b3 + (9 + d) * 256, nullptr, 0, 0, p0, 512, nullptr),
           D(msgb, 256, sw(rsW3b, 2 * d + 1), 256, 256, 256, rs_b3 + (2 * d + 1) * 256, nullptr, 0, 0, p0 + 256, 512, nullptr));
        // node chain
        GB(D(p0, 512, nw1, 512, 512, 512, rc_b1 + d * 512, nullptr, 0, 0, p1, 512, nullptr), Z);
        GB(D(p1, 512, nw2, 512, 512, 512, rc_b2 + d * 512, p0, 512, 512, p2, 512, nullptr), Z);
        GB(D(p2, 512, nw3, 512, 256, 512, rc_b3 + d * 256, nullptr, 0, 0, Tb, 256, nullptr), Z);
        GB(D(Tb, 256, sw(rsW1b, 6 + d), 256, 256, 256, rs_b1 + (6 + d) * 256, nullptr, 0, 0, q0, 256, nullptr), Z);
        GB(D(q0, 256, sw(rsW2b, 6 + d), 256, 256, 256, rs_b2 + (6 + d) * 256, Tb, 256, 256, q1, 256, nullptr), Z);
        GB(D(q1, 256, sw(rsW3b, 6 + d), 256, 256, 256, rs_b3 + (6 + d) * 256, nullptr, 0, 0, ebc, 256,
             out + (size_t)l * NN * HDIM), Z);

        ep = ebc;
        unsigned short* t = ebc; ebc = ebn; ebn = t;
    }
}

// Round 6
// 2219.897 us; speedup vs baseline: 1.3585x; 1.1749x over previous
//
#include <hip/hip_runtime.h>

#define NLVL 6
#define NN   32768
#define KFAN 8
#define FDIM 32
#define HDIM 256

typedef __attribute__((ext_vector_type(4))) float f32x4;
typedef __attribute__((ext_vector_type(8))) _Float16 f16x8;
typedef __attribute__((ext_vector_type(4))) unsigned short u16x4;

__device__ __forceinline__ float h2f(unsigned short u) {
    _Float16 h; __builtin_memcpy(&h, &u, 2); return (float)h;
}
__device__ __forceinline__ unsigned short f2h(float f) {
    _Float16 h = (_Float16)f;   // RNE
    unsigned short u; __builtin_memcpy(&u, &h, 2); return u;
}
__device__ __forceinline__ float tanh_fast(float x) {
    float e = __expf(2.0f * x);
    return 1.0f - 2.0f / (e + 1.0f);
}
__device__ __forceinline__ void gload16(const void* g, void* l) {
    __builtin_amdgcn_global_load_lds((const __attribute__((address_space(1))) void*)g,
                                     (__attribute__((address_space(3))) void*)l, 16, 0, 0);
}

// ---------------------------------------------------------------------------
// Paired fp16 B^T GEMM: out = tanh(A[M,K] @ B[N,K]^T + bias) [+res if col<resW]
// Two GEMMs per launch, selected by block range via FLAT SCALAR args (no
// struct, no reference -> pure s_cselect at entry, nothing in the hot loop).
// Tile 64x128, BK=64, 4 waves (2x2 of 32x64). M fixed = 32768 (512 row-blocks).
// LDS XOR-swizzled both-sides (pre-swizzled global src + swizzled ds_read).
// ---------------------------------------------------------------------------
__global__ __launch_bounds__(256)
void gemm_pair(const unsigned short* __restrict__ A0, const unsigned short* __restrict__ B0,
               const float* __restrict__ bias0, const unsigned short* __restrict__ res0,
               unsigned short* __restrict__ out0, float* __restrict__ outF0,
               int lda0, int ldb0, int ldr0, int ldo0, int resW0, int K0,
               const unsigned short* __restrict__ A1, const unsigned short* __restrict__ B1,
               const float* __restrict__ bias1, const unsigned short* __restrict__ res1,
               unsigned short* __restrict__ out1, float* __restrict__ outF1,
               int lda1, int ldb1, int ldr1, int ldo1, int resW1, int K1,
               int nblk0)
{
    const bool s = (int)blockIdx.x >= nblk0;
    const unsigned short* A    = s ? A1    : A0;
    const unsigned short* B    = s ? B1    : B0;
    const float*          bias = s ? bias1 : bias0;
    const unsigned short* res  = s ? res1  : res0;
    unsigned short*       outB = s ? out1  : out0;
    float*                outF = s ? outF1 : outF0;
    const int lda  = s ? lda1  : lda0;
    const int ldb  = s ? ldb1  : ldb0;
    const int ldr  = s ? ldr1  : ldr0;
    const int ldo  = s ? ldo1  : ldo0;
    const int resW = s ? resW1 : resW0;
    const int K    = s ? K1    : K0;
    const int bx   = (int)blockIdx.x - (s ? nblk0 : 0);
    const int brow = (bx & 511) * 64;
    const int bcol = (bx >> 9) * 128;

    __shared__ __align__(16) unsigned short sA[64 * 64];    //  8 KB
    __shared__ __align__(16) unsigned short sB[128 * 64];   // 16 KB

    const int tid  = threadIdx.x;
    const int wid  = tid >> 6;
    const int lane = tid & 63;
    const int wr   = wid >> 1, wc = wid & 1;        // wave quadrant (2 rows x 2 cols)
    const int fr   = lane & 15, fq = lane >> 4;     // fragment row / k-group
    const int srow = lane >> 3;                     // staging row within chunk
    const int scol = ((lane & 7) ^ srow) * 8;       // pre-swizzled 16B col-block

    f32x4 acc[2][4] = {};

    for (int k0 = 0; k0 < K; k0 += 64) {
        // stage: A = 8 chunks of 1KB (2/wave), B = 16 chunks (4/wave)
        #pragma unroll
        for (int it = 0; it < 2; ++it) {
            const int c = wid * 2 + it;
            gload16(A + (size_t)(brow + c * 8 + srow) * lda + k0 + scol, sA + c * 512);
        }
        #pragma unroll
        for (int it = 0; it < 4; ++it) {
            const int c = wid * 4 + it;
            gload16(B + (size_t)(bcol + c * 8 + srow) * ldb + k0 + scol, sB + c * 512);
        }
        __syncthreads();
        #pragma unroll
        for (int ks = 0; ks < 2; ++ks) {            // two K=32 sub-steps
            f16x8 av[2], bv[4];
            #pragma unroll
            for (int m = 0; m < 2; ++m) {
                const int r = wr * 32 + m * 16 + fr;
                const int b = r * 128 + ((ks * 64 + fq * 16) ^ ((r & 7) << 4));
                av[m] = *(const f16x8*)((const char*)sA + b);
            }
            #pragma unroll
            for (int n = 0; n < 4; ++n) {
                const int r = wc * 64 + n * 16 + fr;
                const int b = r * 128 + ((ks * 64 + fq * 16) ^ ((r & 7) << 4));
                bv[n] = *(const f16x8*)((const char*)sB + b);
            }
            #pragma unroll
            for (int m = 0; m < 2; ++m)
                #pragma unroll
                for (int n = 0; n < 4; ++n)
                    acc[m][n] = __builtin_amdgcn_mfma_f32_16x16x32_f16(av[m], bv[n], acc[m][n], 0, 0, 0);
        }
        __syncthreads();
    }

    // epilogue: C/D layout col = lane&15, row = (lane>>4)*4 + j  [m89-verified]
    #pragma unroll
    for (int m = 0; m < 2; ++m) {
        #pragma unroll
        for (int n = 0; n < 4; ++n) {
            const int col = bcol + wc * 64 + n * 16 + fr;
            const float bb = bias[col];
            #pragma unroll
            for (int j = 0; j < 4; ++j) {
                const int row = brow + wr * 32 + m * 16 + fq * 4 + j;
                float v = acc[m][n][j] + bb;
                v = tanh_fast(v);
                if (res && col < resW) v += h2f(res[(size_t)row * ldr + col]);
                outB[(size_t)row * ldo + col] = f2h(v);
                if (outF) outF[(size_t)row * HDIM + col] = v;
            }
        }
    }
}

// ---------------------------------------------------------------------------
// Embed ALL levels: e_l = tanh(feats[l] @ We^T + be) -> ebuf[l] (fp16);
// level 0 also mirrored to out[0] (f32) since embeds[0] = embed_op(feats[0]).
// ---------------------------------------------------------------------------
__global__ __launch_bounds__(256)
void embed_all(const float* __restrict__ feats,
               const float* __restrict__ We,
               const float* __restrict__ be,
               unsigned short* __restrict__ ebuf,
               float* __restrict__ out0)
{
    __shared__ float sW[256 * 33];   // +1 pad: kills bank conflicts on t*33+k
    __shared__ float sF[16 * 32];
    const int l   = blockIdx.x >> 11;       // / 2048 blocks per level
    const int blk = blockIdx.x & 2047;
    const int t = threadIdx.x;
    #pragma unroll
    for (int i = 0; i < 32; ++i) {
        int idx = t + 256 * i;
        sW[(idx >> 5) * 33 + (idx & 31)] = We[idx];
    }
    const size_t base = (size_t)blk * 16;
    const float* fl = feats + (size_t)l * NN * FDIM;
    for (int i = t; i < 16 * 32; i += 256) sF[i] = fl[base * 32 + i];
    __syncthreads();

    unsigned short* ob = ebuf + (size_t)l * NN * HDIM;
    const float bb = be[t];
    for (int r = 0; r < 16; ++r) {
        float a = bb;
        #pragma unroll
        for (int k = 0; k < 32; ++k) a += sF[r * 32 + k] * sW[t * 33 + k];
        const float v = tanh_fast(a);
        const size_t row = base + r;
        ob[row * HDIM + t] = f2h(v);
        if (l == 0) out0[row * HDIM + t] = v;
    }
}

// ---------------------------------------------------------------------------
// Gather-sum: msg[n,:] = sum_{k<8} e[idx[n,k],:]  (fp16 in, fp32 acc, fp16 out)
// ---------------------------------------------------------------------------
__global__ __launch_bounds__(256)
void gather_kernel(const unsigned short* __restrict__ ehalf,
                   const int* __restrict__ idx,
                   unsigned short* __restrict__ msg)
{
    const int n = blockIdx.x;
    const int t = threadIdx.x;
    const int* row = idx + (size_t)n * KFAN;
    float s = 0.f;
    #pragma unroll
    for (int k = 0; k < KFAN; ++k)
        s += h2f(ehalf[(size_t)row[k] * HDIM + t]);
    msg[(size_t)n * HDIM + t] = f2h(s);
}

// ---------------------------------------------------------------------------
// fp32 -> fp16 weight conversion
// ---------------------------------------------------------------------------
__global__ __launch_bounds__(256)
void cvt_kernel(const float* __restrict__ in, unsigned short* __restrict__ out, int n4)
{
    const int i = blockIdx.x * 256 + threadIdx.x;
    if (i >= n4) return;
    const float4 v = ((const float4*)in)[i];
    u16x4 o;
    o[0] = f2h(v.x); o[1] = f2h(v.y); o[2] = f2h(v.z); o[3] = f2h(v.w);
    ((u16x4*)out)[i] = o;
}

// ---------------------------------------------------------------------------
extern "C" void kernel_launch(void* const* d_in, const int* in_sizes, int n_in,
                              void* d_out, int out_size, void* d_ws, size_t ws_size,
                              hipStream_t stream)
{
    const float* feats    = (const float*)d_in[0];
    const int*   pred_idx = (const int*)d_in[1];
    const float* We       = (const float*)d_in[2];
    const float* be       = (const float*)d_in[3];
    const float* rs_b1    = (const float*)d_in[5];
    const float* rs_b2    = (const float*)d_in[7];
    const float* rs_b3    = (const float*)d_in[9];
    const float* rc_b1    = (const float*)d_in[11];
    const float* rc_b2    = (const float*)d_in[13];
    const float* rc_b3    = (const float*)d_in[15];
    float* out = (float*)d_out;

    // ---- workspace layout (fp16 everywhere) ----
    char* ws = (char*)d_ws;
    size_t off = 0;
    auto alloc = [&](size_t bytes) -> unsigned short* {
        unsigned short* p = (unsigned short*)(ws + off);
        off += (bytes + 255) & ~(size_t)255;
        return p;
    };
    unsigned short* rcW1b = alloc((size_t)6 * 512 * 512 * 2);
    unsigned short* rcW2b = alloc((size_t)6 * 512 * 512 * 2);
    unsigned short* rcW3b = alloc((size_t)6 * 256 * 512 * 2);
    unsigned short* rsW1b = alloc((size_t)12 * 256 * 256 * 2);
    unsigned short* rsW2b = alloc((size_t)12 * 256 * 256 * 2);
    unsigned short* rsW3b = alloc((size_t)12 * 256 * 256 * 2);
    unsigned short* ebuf  = alloc((size_t)NLVL * NN * 256 * 2);  // embed_op all levels
    unsigned short* p0    = alloc((size_t)NN * 512 * 2);   // x2cat = [e', r]
    unsigned short* p1    = alloc((size_t)NN * 512 * 2);   // big h1
    unsigned short* p2    = alloc((size_t)NN * 512 * 2);   // big h2
    unsigned short* Tb    = alloc((size_t)NN * 256 * 2);   // big-resnet outputs
    unsigned short* q0    = alloc((size_t)NN * 256 * 2);
    unsigned short* q1    = alloc((size_t)NN * 256 * 2);
    unsigned short* q2    = alloc((size_t)NN * 256 * 2);
    unsigned short* q3    = alloc((size_t)NN * 256 * 2);
    unsigned short* msgb  = alloc((size_t)NN * 256 * 2);
    unsigned short* ebfA  = alloc((size_t)NN * 256 * 2);
    unsigned short* ebfB  = alloc((size_t)NN * 256 * 2);
    (void)ws_size; (void)in_sizes; (void)n_in; (void)out_size;

    // ---- convert weights fp32 -> fp16 ----
    auto cvt = [&](const float* src, unsigned short* dst, int n) {
        int n4 = n / 4;
        cvt_kernel<<<dim3((n4 + 255) / 256), dim3(256), 0, stream>>>(src, dst, n4);
    };
    cvt((const float*)d_in[10], rcW1b, 6 * 512 * 512);
    cvt((const float*)d_in[12], rcW2b, 6 * 512 * 512);
    cvt((const float*)d_in[14], rcW3b, 6 * 256 * 512);
    cvt((const float*)d_in[4],  rsW1b, 12 * 256 * 256);
    cvt((const float*)d_in[6],  rsW2b, 12 * 256 * 256);
    cvt((const float*)d_in[8],  rsW3b, 12 * 256 * 256);

    // ---- all embed_ops upfront (depend only on feats) ----
    embed_all<<<dim3(NLVL * (NN / 16)), dim3(256), 0, stream>>>(feats, We, be, ebuf, out);

    // ---- flat descriptor for pair launches ----
    struct HD {
        const unsigned short *A, *B; const float* bias; const unsigned short* res;
        unsigned short* ob; float* of; int lda, ldb, ldr, ldo, resW, K, nblk;
    };
    auto D = [&](const unsigned short* A, int lda, const unsigned short* B, int ldb,
                 int N, int K, const float* bias,
                 const unsigned short* res, int ldr, int resW,
                 unsigned short* ob, int ldo, float* of) -> HD {
        HD h; h.A = A; h.B = B; h.bias = bias; h.res = res; h.ob = ob; h.of = of;
        h.lda = lda; h.ldb = ldb; h.ldr = ldr; h.ldo = ldo; h.resW = resW;
        h.K = K; h.nblk = 512 * (N / 128);
        return h;
    };
    auto GB = [&](const HD& a, const HD& b) {   // host-side only; device gets flat args
        gemm_pair<<<dim3(a.nblk + b.nblk), dim3(256), 0, stream>>>(
            a.A, a.B, a.bias, a.res, a.ob, a.of, a.lda, a.ldb, a.ldr, a.ldo, a.resW, a.K,
            b.A, b.B, b.bias, b.res, b.ob, b.of, b.lda, b.ldb, b.ldr, b.ldo, b.resW, b.K,
            a.nblk);
    };
    auto G1 = [&](const HD& a) {
        gemm_pair<<<dim3(a.nblk), dim3(256), 0, stream>>>(
            a.A, a.B, a.bias, a.res, a.ob, a.of, a.lda, a.ldb, a.ldr, a.ldo, a.resW, a.K,
            a.A, a.B, a.bias, a.res, a.ob, a.of, a.lda, a.ldb, a.ldr, a.ldo, a.resW, a.K,
            a.nblk);
    };

    const unsigned short* ep = ebuf;   // embeds[l-1]: level 0 final = embed_op(0)
    unsigned short* ebc = ebfA;
    unsigned short* ebn = ebfB;

    for (int l = 1; l < NLVL; ++l) {
        const int d = (l - 1 < 2) ? (l - 1) : 2;
        const unsigned short* el = ebuf + (size_t)l * NN * 256;  // embed_op(l)
        const int* idx_l = pred_idx + (size_t)(l - 1) * NN * KFAN;

        const unsigned short* cw1 = rcW1b + (size_t)(3 + d) * 512 * 512;
        const unsigned short* cw2 = rcW2b + (size_t)(3 + d) * 512 * 512;
        const unsigned short* cw3 = rcW3b + (size_t)(3 + d) * 256 * 512;
        const unsigned short* nw1 = rcW1b + (size_t)d * 512 * 512;
        const unsigned short* nw2 = rcW2b + (size_t)d * 512 * 512;
        const unsigned short* nw3 = rcW3b + (size_t)d * 256 * 512;
        auto sw = [&](const unsigned short* base, int i) { return base + (size_t)i * 256 * 256; };

        // msg gather (msgb <- sum of predecessor embeds from prev level)
        gather_kernel<<<dim3(NN), dim3(256), 0, stream>>>(ep, idx_l, msgb);

        // C1 || M1    (comb big layer1: x=[e,0] -> K=256 on first 256 W-cols)
        GB(D(el, 256, cw1, 512, 512, 256, rc_b1 + (3 + d) * 512, nullptr, 0, 0, p1, 512, nullptr),
           D(msgb, 256, sw(rsW1b, 2 * d), 256, 256, 256, rs_b1 + (2 * d) * 256, nullptr, 0, 0, q0, 256, nullptr));
        // C2 || M2
        GB(D(p1, 512, cw2, 512, 512, 512, rc_b2 + (3 + d) * 512, el, 256, 256, p2, 512, nullptr),
           D(q0, 256, sw(rsW2b, 2 * d), 256, 256, 256, rs_b2 + (2 * d) * 256, msgb, 256, 256, q1, 256, nullptr));
        // C3 || M3
        GB(D(p2, 512, cw3, 512, 256, 512, rc_b3 + (3 + d) * 256, nullptr, 0, 0, Tb, 256, nullptr),
           D(q1, 256, sw(rsW3b, 2 * d), 256, 256, 256, rs_b3 + (2 * d) * 256, nullptr, 0, 0, q2, 256, nullptr));
        // S1 || M4
        GB(D(Tb, 256, sw(rsW1b, 9 + d), 256, 256, 256, rs_b1 + (9 + d) * 256, nullptr, 0, 0, q0, 256, nullptr),
           D(q2, 256, sw(rsW1b, 2 * d + 1), 256, 256, 256, rs_b1 + (2 * d + 1) * 256, nullptr, 0, 0, q3, 256, nullptr));
        // S2 || M5
        GB(D(q0, 256, sw(rsW2b, 9 + d), 256, 256, 256, rs_b2 + (9 + d) * 256, Tb, 256, 256, q1, 256, nullptr),
           D(q3, 256, sw(rsW2b, 2 * d + 1), 256, 256, 256, rs_b2 + (2 * d + 1) * 256, q2, 256, 256, msgb, 256, nullptr));
        // S3 || M6   -> p0 = [e', r]
        GB(D(q1, 256, sw(rsW3b, 9 + d), 256, 256, 256, rs_b3 + (9 + d) * 256, nullptr, 0, 0, p0, 512, nullptr),
           D(msgb, 256, sw(rsW3b, 2 * d + 1), 256, 256, 256, rs_b3 + (2 * d + 1) * 256, nullptr, 0, 0, p0 + 256, 512, nullptr));
        // node chain (solo launches)
        G1(D(p0, 512, nw1, 512, 512, 512, rc_b1 + d * 512, nullptr, 0, 0, p1, 512, nullptr));
        G1(D(p1, 512, nw2, 512, 512, 512, rc_b2 + d * 512, p0, 512, 512, p2, 512, nullptr));
        G1(D(p2, 512, nw3, 512, 256, 512, rc_b3 + d * 256, nullptr, 0, 0, Tb, 256, nullptr));
        G1(D(Tb, 256, sw(rsW1b, 6 + d), 256, 256, 256, rs_b1 + (6 + d) * 256, nullptr, 0, 0, q0, 256, nullptr));
        G1(D(q0, 256, sw(rsW2b, 6 + d), 256, 256, 256, rs_b2 + (6 + d) * 256, Tb, 256, 256, q1, 256, nullptr));
        G1(D(q1, 256, sw(rsW3b, 6 + d), 256, 256, 256, rs_b3 + (6 + d) * 256, nullptr, 0, 0, ebc, 256,
             out + (size_t)l * NN * HDIM));

        ep = ebc;
        unsigned short* t = ebc; ebc = ebn; ebn = t;
    }
}